// Round 4
// baseline (13587.462 us; speedup 1.0000x reference)
//
#include <hip/hip_runtime.h>
#include <stdint.h>

// Bidirectional LSTM T=4096, B=1, I=H=1024 -> 3 classes.
// R4: Whh lives in LDS (128 KB/block, XOR-swizzled, 1 block/CU) -- removes the
//     scratch-spill restream that R3's rocprof exposed (VGPR=52 => whh spilled).
//     Phase 1 GEMM precomputes xg = x*Wih^T + bias into ws (unchanged).
//     Packed (epoch|h) u64 dataflow sync (unchanged).

#define T_SEQ 4096
#define ISZ   1024
#define HID   1024
#define NB_DIR 128
#define NB_TOT 256
#define NTHR  512
#define PAD   68

typedef unsigned long long u64;

__device__ __forceinline__ float fast_sigmoid(float x) {
    return 1.0f / (1.0f + __expf(-x));
}
__device__ __forceinline__ float fast_tanh(float x) {
    return 1.0f - 2.0f / (__expf(2.0f * x) + 1.0f);
}

// ---------------- Phase 1: xg[dir][t][g] = dot(x[row(t)], Wih[g]) + bih[g] + bhh[g]
#define GM 64
#define GN 64
#define GK 32

__global__ __launch_bounds__(256)
void xproj_gemm(const float* __restrict__ x,
                const float* __restrict__ Wih_f, const float* __restrict__ bih_f,
                const float* __restrict__ bhh_f,
                const float* __restrict__ Wih_b, const float* __restrict__ bih_b,
                const float* __restrict__ bhh_b,
                float* __restrict__ xg)
{
    const int dir = blockIdx.z;
    const float* Wih = dir ? Wih_b : Wih_f;
    const float* bih = dir ? bih_b : bih_f;
    const float* bhh = dir ? bhh_b : bhh_f;
    const int m0 = blockIdx.y * GM;   // t-tile
    const int n0 = blockIdx.x * GN;   // gate-row tile
    const int tid = threadIdx.x;
    const int ms = tid >> 2;          // 0..63 staging row
    const int kq = tid & 3;           // 0..3 staging k-quarter
    const int tm = tid >> 4;          // 0..15 micro-tile row group
    const int tn = tid & 15;          // 0..15 micro-tile col group

    __shared__ float As[GK][GM + 4];
    __shared__ float Bs[GK][GN + 4];

    float acc[4][4] = {};

    const int mrow = m0 + ms;
    const int xrow = dir ? (T_SEQ - 1 - mrow) : mrow;
    const float* ap = x + (size_t)xrow * ISZ + kq * 8;
    const float* bp = Wih + (size_t)(n0 + ms) * ISZ + kq * 8;

    for (int k0 = 0; k0 < ISZ; k0 += GK) {
        float4 a0 = *(const float4*)(ap + k0);
        float4 a1 = *(const float4*)(ap + k0 + 4);
        float4 b0 = *(const float4*)(bp + k0);
        float4 b1 = *(const float4*)(bp + k0 + 4);
        __syncthreads();
        const int kb = kq * 8;
        As[kb+0][ms]=a0.x; As[kb+1][ms]=a0.y; As[kb+2][ms]=a0.z; As[kb+3][ms]=a0.w;
        As[kb+4][ms]=a1.x; As[kb+5][ms]=a1.y; As[kb+6][ms]=a1.z; As[kb+7][ms]=a1.w;
        Bs[kb+0][ms]=b0.x; Bs[kb+1][ms]=b0.y; Bs[kb+2][ms]=b0.z; Bs[kb+3][ms]=b0.w;
        Bs[kb+4][ms]=b1.x; Bs[kb+5][ms]=b1.y; Bs[kb+6][ms]=b1.z; Bs[kb+7][ms]=b1.w;
        __syncthreads();
        #pragma unroll
        for (int k = 0; k < GK; ++k) {
            float4 av = *(const float4*)&As[k][tm * 4];
            float4 bv = *(const float4*)&Bs[k][tn * 4];
            acc[0][0] += av.x*bv.x; acc[0][1] += av.x*bv.y; acc[0][2] += av.x*bv.z; acc[0][3] += av.x*bv.w;
            acc[1][0] += av.y*bv.x; acc[1][1] += av.y*bv.y; acc[1][2] += av.y*bv.z; acc[1][3] += av.y*bv.w;
            acc[2][0] += av.z*bv.x; acc[2][1] += av.z*bv.y; acc[2][2] += av.z*bv.z; acc[2][3] += av.z*bv.w;
            acc[3][0] += av.w*bv.x; acc[3][1] += av.w*bv.y; acc[3][2] += av.w*bv.z; acc[3][3] += av.w*bv.w;
        }
    }

    const int gc = n0 + tn * 4;
    float4 bb1 = *(const float4*)(bih + gc);
    float4 bb2 = *(const float4*)(bhh + gc);
    float bx = bb1.x + bb2.x, by = bb1.y + bb2.y, bz = bb1.z + bb2.z, bw = bb1.w + bb2.w;
    float* op = xg + ((size_t)dir << 24) + (size_t)(m0 + tm * 4) * 4096 + gc;
    #pragma unroll
    for (int i = 0; i < 4; ++i) {
        float4 v;
        v.x = acc[i][0] + bx; v.y = acc[i][1] + by;
        v.z = acc[i][2] + bz; v.w = acc[i][3] + bw;
        *(float4*)(op + (size_t)i * 4096) = v;
    }
}

// ---------------- Phase 2: persistent recurrence, Whh in LDS
__global__ __launch_bounds__(NTHR, 2)
void bilstm_rec(const float* __restrict__ xg,
                const float* __restrict__ Whh_f, const float* __restrict__ Whh_b,
                u64* hpack)
{
    const int tid = threadIdx.x;
    const int blk = blockIdx.x;
    const int dir = blk >> 7;
    const int lb  = blk & 127;
    const int u0  = lb * 8;
    const int w   = tid >> 6;        // wave 0..7 -> unit u0+w
    const int lane = tid & 63;
    const int q   = lane >> 4;       // gate 0..3 (i,f,g,o)
    const int kc  = lane & 15;       // k-chunk
    const int grow = q * HID + u0 + w;

    const float* Whh = dir ? Whh_b : Whh_f;
    const float* xgd = xg + ((size_t)dir << 24);
    u64* hp = hpack + (size_t)dir * 2 * HID;

    // 32 rows x 1024 floats = 128 KB, XOR-swizzled for conflict-free b128 reads
    __shared__ float wlds[32 * 1024];
    __shared__ float lds_h[2][16 * PAD];

    // Per-lane swizzle: spreads the 64 lanes of each read across all 8
    // bank-groups; self-cancels on read so values come back in k-order.
    const int lane_xor = (q << 3) | ((kc & 1) << 2);
    const int r = q * 8 + w;

    // ---- one-time: stage Whh rows into LDS (swizzled) ----
    {
        const float* src = Whh + (size_t)grow * HID + kc * 64;
        float* dstrow = &wlds[r * 1024 + kc * 64];
        #pragma unroll
        for (int jj = 0; jj < 64; jj += 4) {
            float4 v = *(const float4*)(src + jj);
            *(float4*)(dstrow + (jj ^ lane_xor)) = v;
        }
    }

    float c_state = 0.0f;            // lane 0 of each wave
    float xgv = 0.0f;
    if (kc == 0) xgv = xgd[grow];    // t=0 row
    asm volatile("" : "+v"(xgv));
    __syncthreads();                 // wlds ready

    const float* wrow = &wlds[r * 1024 + kc * 64];
    bool dead = false;

    for (int t = 0; t < T_SEQ; ++t) {
        float pre = 0.0f;

        if (t > 0) {
            const int b = (t - 1) & 1;
            u64* src = hp + (size_t)b * HID;
            const int pi = tid * 2;
            u64 e0 = 0, e1 = 0;
            if (!dead) {
                int sp = 0;
                while (((e0 = __hip_atomic_load(src + pi, __ATOMIC_RELAXED,
                                                __HIP_MEMORY_SCOPE_AGENT)) >> 32)
                       != (unsigned)t) {
                    if (++sp > (1 << 21)) { dead = true; break; }
                }
                sp = 0;
                if (!dead) {
                    while (((e1 = __hip_atomic_load(src + pi + 1, __ATOMIC_RELAXED,
                                                    __HIP_MEMORY_SCOPE_AGENT)) >> 32)
                           != (unsigned)t) {
                        if (++sp > (1 << 21)) { dead = true; break; }
                    }
                }
            }
            float2 hv;
            hv.x = __uint_as_float((unsigned)(e0 & 0xffffffffu));
            hv.y = __uint_as_float((unsigned)(e1 & 0xffffffffu));
            *(float2*)&lds_h[b][(pi >> 6) * PAD + (pi & 63)] = hv;
            __syncthreads();
            const float* lh = &lds_h[b][kc * PAD];
            #pragma unroll
            for (int j = 0; j < 16; ++j) {
                float4 wv = *(const float4*)(wrow + ((4 * j) ^ lane_xor));
                float4 hv4 = *(const float4*)(lh + 4 * j);
                pre += wv.x*hv4.x + wv.y*hv4.y + wv.z*hv4.z + wv.w*hv4.w;
            }
        }

        // reduce over the 16 k-chunk lanes (low 4 lane bits)
        pre += __shfl_xor(pre, 1);
        pre += __shfl_xor(pre, 2);
        pre += __shfl_xor(pre, 4);
        pre += __shfl_xor(pre, 8);

        float pg = pre + xgv;        // valid at lanes 0,16,32,48 (kc==0)

        // gather the 4 gates of this wave's unit to lane 0
        float pf_g = __shfl(pg, 16);
        float pg_g = __shfl(pg, 32);
        float po_g = __shfl(pg, 48);

        if (lane == 0) {
            float si = fast_sigmoid(pg);
            float sf = fast_sigmoid(pf_g);
            float tg = fast_tanh(pg_g);
            float so = fast_sigmoid(po_g);
            c_state = sf * c_state + si * tg;
            float hval = so * fast_tanh(c_state);
            u64 pk = ((u64)(unsigned)(t + 1) << 32) | (u64)__float_as_uint(hval);
            __hip_atomic_store(hp + (size_t)(t & 1) * HID + u0 + w, pk,
                               __ATOMIC_RELAXED, __HIP_MEMORY_SCOPE_AGENT);
        }

        // prefetch next xg row (L3-resident; hides under next poll window)
        if (t + 1 < T_SEQ) {
            if (kc == 0) {
                xgv = xgd[(size_t)(t + 1) * 4096 + grow];
                asm volatile("" : "+v"(xgv));
            }
        }
    }
}

// ---------------- head
__global__ void head_kernel(const float* __restrict__ W_ho,
                            const float* __restrict__ b_ho,
                            const u64* __restrict__ hpack,
                            float* __restrict__ out)
{
    const u64* hf  = hpack + 1 * HID;            // dir0 buf1
    const u64* hbk = hpack + 2 * HID + 1 * HID;  // dir1 buf1
    __shared__ float r0[4], r1[4], r2[4];
    int tid = threadIdx.x;  // 256
    float p0 = 0.f, p1 = 0.f, p2 = 0.f;
    for (int i = tid; i < 2 * HID; i += 256) {
        u64 e = (i < HID) ? hf[i] : hbk[i - HID];
        float hv = __uint_as_float((unsigned)(e & 0xffffffffu));
        p0 += W_ho[0 * 2 * HID + i] * hv;
        p1 += W_ho[1 * 2 * HID + i] * hv;
        p2 += W_ho[2 * 2 * HID + i] * hv;
    }
    #pragma unroll
    for (int m = 1; m < 64; m <<= 1) {
        p0 += __shfl_xor(p0, m);
        p1 += __shfl_xor(p1, m);
        p2 += __shfl_xor(p2, m);
    }
    int w = tid >> 6;
    if ((tid & 63) == 0) { r0[w] = p0; r1[w] = p1; r2[w] = p2; }
    __syncthreads();
    if (tid == 0) {
        out[0] = b_ho[0] + r0[0] + r0[1] + r0[2] + r0[3];
        out[1] = b_ho[1] + r1[0] + r1[1] + r1[2] + r1[3];
        out[2] = b_ho[2] + r2[0] + r2[1] + r2[2] + r2[3];
    }
}

// ---------------- fallback (only if ws too small; never expected) ----------------
#define ROWS_PER_BLK 32
#define UNITS_PER_BLK 8
#define KW 64

__global__ __launch_bounds__(NTHR, 2)
void bilstm_fallback(const float* __restrict__ x,
                     const float* __restrict__ Wih_f, const float* __restrict__ Whh_f,
                     const float* __restrict__ bih_f, const float* __restrict__ bhh_f,
                     const float* __restrict__ Wih_b, const float* __restrict__ Whh_b,
                     const float* __restrict__ bih_b, const float* __restrict__ bhh_b,
                     u64* hpack)
{
    const int tid = threadIdx.x;
    const int blk = blockIdx.x;
    const int dir = blk >> 7;
    const int lb  = blk & 127;
    const int u0  = lb * UNITS_PER_BLK;
    const int r_local = tid >> 4;
    const int kc  = tid & 15;
    const int q   = r_local >> 3;
    const int uu  = r_local & 7;
    const int grow = q * HID + u0 + uu;

    const float* Wih = dir ? Wih_b : Wih_f;
    const float* Whh = dir ? Whh_b : Whh_f;
    const float* bih = dir ? bih_b : bih_f;
    const float* bhh = dir ? bhh_b : bhh_f;
    u64* hp = hpack + (size_t)dir * 2 * HID;

    __shared__ float lds_h[16 * PAD];
    __shared__ float lds_x[16 * PAD];
    __shared__ float lds_g[ROWS_PER_BLK];
    __shared__ float lds_bias[ROWS_PER_BLK];

    float wih[KW], whh[KW];
    {
        const float* pih = Wih + (size_t)grow * ISZ + kc * KW;
        const float* phh = Whh + (size_t)grow * HID + kc * KW;
        #pragma unroll
        for (int j = 0; j < KW; j += 4) {
            float4 a = *(const float4*)(pih + j);
            wih[j] = a.x; wih[j+1] = a.y; wih[j+2] = a.z; wih[j+3] = a.w;
            float4 b4 = *(const float4*)(phh + j);
            whh[j] = b4.x; whh[j+1] = b4.y; whh[j+2] = b4.z; whh[j+3] = b4.w;
        }
    }
    if (tid < ROWS_PER_BLK) {
        int qq = tid >> 3, u2 = tid & 7;
        int gr = qq * HID + u0 + u2;
        lds_bias[tid] = bih[gr] + bhh[gr];
    }
    float c_state = 0.0f;
    {
        int xrow = dir ? (T_SEQ - 1) : 0;
        const float* xp = x + (size_t)xrow * ISZ;
        int i0 = tid * 2;
        float2 v = *(const float2*)(xp + i0);
        *(float2*)&lds_x[(i0 >> 6) * PAD + (i0 & 63)] = v;
    }
    __syncthreads();
    float xacc = 0.0f;
    {
        const float* lx = lds_x + kc * PAD;
        #pragma unroll
        for (int j = 0; j < KW; j += 4) {
            float4 v = *(const float4*)(lx + j);
            xacc += wih[j]*v.x + wih[j+1]*v.y + wih[j+2]*v.z + wih[j+3]*v.w;
        }
    }
    bool dead = false;
    for (int t = 0; t < T_SEQ; ++t) {
        float pre = xacc;
        if (t > 0) {
            u64* src = hp + ((size_t)((t - 1) & 1)) * HID;
            const int pi = tid * 2;
            u64 e0 = 0, e1 = 0;
            if (!dead) {
                int sp = 0;
                while (((e0 = __hip_atomic_load(src + pi, __ATOMIC_RELAXED,
                                                __HIP_MEMORY_SCOPE_AGENT)) >> 32) != (unsigned)t) {
                    if (++sp > (1 << 21)) { dead = true; break; }
                }
                sp = 0;
                if (!dead) {
                    while (((e1 = __hip_atomic_load(src + pi + 1, __ATOMIC_RELAXED,
                                                    __HIP_MEMORY_SCOPE_AGENT)) >> 32) != (unsigned)t) {
                        if (++sp > (1 << 21)) { dead = true; break; }
                    }
                }
            }
            lds_h[(pi >> 6) * PAD + (pi & 63)] = __uint_as_float((unsigned)(e0 & 0xffffffffu));
            lds_h[((pi + 1) >> 6) * PAD + ((pi + 1) & 63)] = __uint_as_float((unsigned)(e1 & 0xffffffffu));
            __syncthreads();
            const float* lh = lds_h + kc * PAD;
            #pragma unroll
            for (int j = 0; j < KW; j += 4) {
                float4 v = *(const float4*)(lh + j);
                pre += whh[j]*v.x + whh[j+1]*v.y + whh[j+2]*v.z + whh[j+3]*v.w;
            }
        }
        pre += __shfl_xor(pre, 1);
        pre += __shfl_xor(pre, 2);
        pre += __shfl_xor(pre, 4);
        pre += __shfl_xor(pre, 8);
        if (kc == 0) lds_g[r_local] = pre + lds_bias[r_local];
        __syncthreads();
        if (tid < UNITS_PER_BLK) {
            float gi = lds_g[0 * 8 + tid];
            float gf = lds_g[1 * 8 + tid];
            float gg = lds_g[2 * 8 + tid];
            float go = lds_g[3 * 8 + tid];
            float si = fast_sigmoid(gi);
            float sf = fast_sigmoid(gf);
            float so = fast_sigmoid(go);
            float tg = fast_tanh(gg);
            c_state = sf * c_state + si * tg;
            float hval = so * fast_tanh(c_state);
            u64 pk = ((u64)(unsigned)(t + 1) << 32) | (u64)__float_as_uint(hval);
            __hip_atomic_store(hp + ((size_t)(t & 1)) * HID + u0 + tid, pk,
                               __ATOMIC_RELAXED, __HIP_MEMORY_SCOPE_AGENT);
        }
        if (t + 1 < T_SEQ) {
            int xrow = dir ? (T_SEQ - 2 - t) : (t + 1);
            const float* xp = x + (size_t)xrow * ISZ;
            int i0 = tid * 2;
            float2 v = *(const float2*)(xp + i0);
            *(float2*)&lds_x[(i0 >> 6) * PAD + (i0 & 63)] = v;
            __syncthreads();
            xacc = 0.0f;
            const float* lx = lds_x + kc * PAD;
            #pragma unroll
            for (int j = 0; j < KW; j += 4) {
                float4 v4 = *(const float4*)(lx + j);
                xacc += wih[j]*v4.x + wih[j+1]*v4.y + wih[j+2]*v4.z + wih[j+3]*v4.w;
            }
        }
    }
}

extern "C" void kernel_launch(void* const* d_in, const int* in_sizes, int n_in,
                              void* d_out, int out_size, void* d_ws, size_t ws_size,
                              hipStream_t stream) {
    const float* x     = (const float*)d_in[0];
    const float* Wih_f = (const float*)d_in[1];
    const float* Whh_f = (const float*)d_in[2];
    const float* bih_f = (const float*)d_in[3];
    const float* bhh_f = (const float*)d_in[4];
    const float* Wih_b = (const float*)d_in[5];
    const float* Whh_b = (const float*)d_in[6];
    const float* bih_b = (const float*)d_in[7];
    const float* bhh_b = (const float*)d_in[8];
    const float* W_ho  = (const float*)d_in[9];
    const float* b_ho  = (const float*)d_in[10];

    u64* hpack = (u64*)d_ws;                              // 32 KB
    float* xg = (float*)((char*)d_ws + 32768);            // 128 MB
    const size_t need = 32768 + (size_t)2 * T_SEQ * 4096 * sizeof(float);

    hipMemsetAsync(d_ws, 0, 2 * 2 * HID * sizeof(u64), stream);

    if (ws_size >= need) {
        dim3 gg(4096 / GN, T_SEQ / GM, 2);
        xproj_gemm<<<gg, 256, 0, stream>>>(x, Wih_f, bih_f, bhh_f,
                                           Wih_b, bih_b, bhh_b, xg);
        bilstm_rec<<<NB_TOT, NTHR, 0, stream>>>(xg, Whh_f, Whh_b, hpack);
    } else {
        bilstm_fallback<<<NB_TOT, NTHR, 0, stream>>>(
            x, Wih_f, Whh_f, bih_f, bhh_f, Wih_b, Whh_b, bih_b, bhh_b, hpack);
    }
    head_kernel<<<1, 256, 0, stream>>>(W_ho, b_ho, hpack, (float*)d_out);
}

// Round 5
// 9290.691 us; speedup vs baseline: 1.4625x; 1.4625x over previous
//
#include <hip/hip_runtime.h>
#include <stdint.h>

// Bidirectional LSTM T=4096, B=1, I=H=1024 -> 3 classes.
// R5: weights in NAMED float4 registers (no arrays, no asm-in-loop -- R3/R4
//     post-mortem: pin-loop inhibited unroll => alloca => scratch restream).
//     One wave per hidden unit: lane l owns k in [16l,16l+16) for all 4 gates.
//     h staged in LDS with octet-correct XOR swizzle (R4's was 4-way per octet).
//     Packed (epoch|h) u64 dataflow sync; xg precomputed by fp32 GEMM phase.

#define T_SEQ 4096
#define ISZ   1024
#define HID   1024
#define NB_TOT 256
#define NTHR  512

typedef unsigned long long u64;

__device__ __forceinline__ float fast_sigmoid(float x) {
    return 1.0f / (1.0f + __expf(-x));
}
__device__ __forceinline__ float fast_tanh(float x) {
    return 1.0f - 2.0f / (__expf(2.0f * x) + 1.0f);
}

#define PIN4(v) asm volatile("" : "+v"(v.x), "+v"(v.y), "+v"(v.z), "+v"(v.w))
#define DOT4(a, b) ((a).x*(b).x + (a).y*(b).y + (a).z*(b).z + (a).w*(b).w)

// ---------------- Phase 1: xg[dir][t][g] = dot(x[row(t)], Wih[g]) + bih[g] + bhh[g]
#define GM 64
#define GN 64
#define GK 32

__global__ __launch_bounds__(256)
void xproj_gemm(const float* __restrict__ x,
                const float* __restrict__ Wih_f, const float* __restrict__ bih_f,
                const float* __restrict__ bhh_f,
                const float* __restrict__ Wih_b, const float* __restrict__ bih_b,
                const float* __restrict__ bhh_b,
                float* __restrict__ xg)
{
    const int dir = blockIdx.z;
    const float* Wih = dir ? Wih_b : Wih_f;
    const float* bih = dir ? bih_b : bih_f;
    const float* bhh = dir ? bhh_b : bhh_f;
    const int m0 = blockIdx.y * GM;
    const int n0 = blockIdx.x * GN;
    const int tid = threadIdx.x;
    const int ms = tid >> 2;
    const int kq = tid & 3;
    const int tm = tid >> 4;
    const int tn = tid & 15;

    __shared__ float As[GK][GM + 4];
    __shared__ float Bs[GK][GN + 4];

    float acc[4][4] = {};

    const int mrow = m0 + ms;
    const int xrow = dir ? (T_SEQ - 1 - mrow) : mrow;
    const float* ap = x + (size_t)xrow * ISZ + kq * 8;
    const float* bp = Wih + (size_t)(n0 + ms) * ISZ + kq * 8;

    for (int k0 = 0; k0 < ISZ; k0 += GK) {
        float4 a0 = *(const float4*)(ap + k0);
        float4 a1 = *(const float4*)(ap + k0 + 4);
        float4 b0 = *(const float4*)(bp + k0);
        float4 b1 = *(const float4*)(bp + k0 + 4);
        __syncthreads();
        const int kb = kq * 8;
        As[kb+0][ms]=a0.x; As[kb+1][ms]=a0.y; As[kb+2][ms]=a0.z; As[kb+3][ms]=a0.w;
        As[kb+4][ms]=a1.x; As[kb+5][ms]=a1.y; As[kb+6][ms]=a1.z; As[kb+7][ms]=a1.w;
        Bs[kb+0][ms]=b0.x; Bs[kb+1][ms]=b0.y; Bs[kb+2][ms]=b0.z; Bs[kb+3][ms]=b0.w;
        Bs[kb+4][ms]=b1.x; Bs[kb+5][ms]=b1.y; Bs[kb+6][ms]=b1.z; Bs[kb+7][ms]=b1.w;
        __syncthreads();
        #pragma unroll
        for (int k = 0; k < GK; ++k) {
            float4 av = *(const float4*)&As[k][tm * 4];
            float4 bv = *(const float4*)&Bs[k][tn * 4];
            acc[0][0] += av.x*bv.x; acc[0][1] += av.x*bv.y; acc[0][2] += av.x*bv.z; acc[0][3] += av.x*bv.w;
            acc[1][0] += av.y*bv.x; acc[1][1] += av.y*bv.y; acc[1][2] += av.y*bv.z; acc[1][3] += av.y*bv.w;
            acc[2][0] += av.z*bv.x; acc[2][1] += av.z*bv.y; acc[2][2] += av.z*bv.z; acc[2][3] += av.z*bv.w;
            acc[3][0] += av.w*bv.x; acc[3][1] += av.w*bv.y; acc[3][2] += av.w*bv.z; acc[3][3] += av.w*bv.w;
        }
    }

    const int gc = n0 + tn * 4;
    float4 bb1 = *(const float4*)(bih + gc);
    float4 bb2 = *(const float4*)(bhh + gc);
    float bx = bb1.x + bb2.x, by = bb1.y + bb2.y, bz = bb1.z + bb2.z, bw = bb1.w + bb2.w;
    float* op = xg + ((size_t)dir << 24) + (size_t)(m0 + tm * 4) * 4096 + gc;
    #pragma unroll
    for (int i = 0; i < 4; ++i) {
        float4 v;
        v.x = acc[i][0] + bx; v.y = acc[i][1] + by;
        v.z = acc[i][2] + bz; v.w = acc[i][3] + bw;
        *(float4*)(op + (size_t)i * 4096) = v;
    }
}

// ---------------- Phase 2: persistent recurrence, register-resident Whh
__global__ __launch_bounds__(NTHR, 2)
void bilstm_rec(const float* __restrict__ xg,
                const float* __restrict__ Whh_f, const float* __restrict__ Whh_b,
                u64* hpack)
{
    const int tid = threadIdx.x;
    const int blk = blockIdx.x;
    const int dir = blk >> 7;
    const int lb  = blk & 127;
    const int u0  = lb * 8;
    const int w   = tid >> 6;      // wave index -> unit u0+w
    const int l   = tid & 63;      // lane: owns k in [16l, 16l+16) for 4 gates
    const int unit = u0 + w;
    const int xsh = ((l >> 1) & 3) << 2;   // read-side float-offset XOR

    const float* Whh = dir ? Whh_b : Whh_f;
    const float* xgd = xg + ((size_t)dir << 24);
    u64* hp = hpack + (size_t)dir * 2 * HID;

    __shared__ __align__(16) float lds_h[2][HID];

    // ---- one-time: 16 NAMED float4 weight fragments (64 floats) ----
    const float* wp0 = Whh + (size_t)(0 * HID + unit) * HID + l * 16;
    const float* wp1 = Whh + (size_t)(1 * HID + unit) * HID + l * 16;
    const float* wp2 = Whh + (size_t)(2 * HID + unit) * HID + l * 16;
    const float* wp3 = Whh + (size_t)(3 * HID + unit) * HID + l * 16;
    float4 w00 = *(const float4*)(wp0 + 0),  w01 = *(const float4*)(wp0 + 4);
    float4 w02 = *(const float4*)(wp0 + 8),  w03 = *(const float4*)(wp0 + 12);
    float4 w10 = *(const float4*)(wp1 + 0),  w11 = *(const float4*)(wp1 + 4);
    float4 w12 = *(const float4*)(wp1 + 8),  w13 = *(const float4*)(wp1 + 12);
    float4 w20 = *(const float4*)(wp2 + 0),  w21 = *(const float4*)(wp2 + 4);
    float4 w22 = *(const float4*)(wp2 + 8),  w23 = *(const float4*)(wp2 + 12);
    float4 w30 = *(const float4*)(wp3 + 0),  w31 = *(const float4*)(wp3 + 4);
    float4 w32 = *(const float4*)(wp3 + 8),  w33 = *(const float4*)(wp3 + 12);
    PIN4(w00); PIN4(w01); PIN4(w02); PIN4(w03);
    PIN4(w10); PIN4(w11); PIN4(w12); PIN4(w13);
    PIN4(w20); PIN4(w21); PIN4(w22); PIN4(w23);
    PIN4(w30); PIN4(w31); PIN4(w32); PIN4(w33);

    float c_state = 0.0f;          // lane 0 of each wave
    float xgv = 0.0f;              // lanes 0..3 carry gate 0..3 bias+x proj
    if (l < 4) xgv = xgd[(size_t)l * HID + unit];
    asm volatile("" : "+v"(xgv));

    bool dead = false;

    for (int t = 0; t < T_SEQ; ++t) {
        float s0 = 0.f, s1 = 0.f, s2 = 0.f, s3 = 0.f;

        if (t > 0) {
            // ---- stage h(t-1): poll 2 packed words, write swizzled to LDS ----
            const int b = (t - 1) & 1;
            u64* src = hp + (size_t)b * HID;
            const int k0 = tid * 2;
            u64 e0 = 0, e1 = 0;
            if (!dead) {
                int sp = 0;
                while (((e0 = __hip_atomic_load(src + k0, __ATOMIC_RELAXED,
                                                __HIP_MEMORY_SCOPE_AGENT)) >> 32)
                       != (unsigned)t) {
                    if (++sp > (1 << 21)) { dead = true; break; }
                }
                sp = 0;
                if (!dead) {
                    while (((e1 = __hip_atomic_load(src + k0 + 1, __ATOMIC_RELAXED,
                                                    __HIP_MEMORY_SCOPE_AGENT)) >> 32)
                           != (unsigned)t) {
                        if (++sp > (1 << 21)) { dead = true; break; }
                    }
                }
            }
            // store-side swizzle: element k -> (k & ~15) | ((k&15) ^ (((k>>5)&3)<<2))
            const int mi = (k0 & ~15) | ((k0 & 15) ^ (((k0 >> 5) & 3) << 2));
            float2 hv;
            hv.x = __uint_as_float((unsigned)(e0 & 0xffffffffu));
            hv.y = __uint_as_float((unsigned)(e1 & 0xffffffffu));
            *(float2*)&lds_h[b][mi] = hv;
            __syncthreads();

            // ---- 4 conflict-free b128 reads of this lane's 16-float h chunk ----
            const float* lh = &lds_h[b][l * 16];
            float4 h0 = *(const float4*)(lh + (0  ^ xsh));
            float4 h1 = *(const float4*)(lh + (4  ^ xsh));
            float4 h2 = *(const float4*)(lh + (8  ^ xsh));
            float4 h3 = *(const float4*)(lh + (12 ^ xsh));

            s0 = DOT4(w00,h0) + DOT4(w01,h1) + DOT4(w02,h2) + DOT4(w03,h3);
            s1 = DOT4(w10,h0) + DOT4(w11,h1) + DOT4(w12,h2) + DOT4(w13,h3);
            s2 = DOT4(w20,h0) + DOT4(w21,h1) + DOT4(w22,h2) + DOT4(w23,h3);
            s3 = DOT4(w30,h0) + DOT4(w31,h1) + DOT4(w32,h2) + DOT4(w33,h3);
        }

        // ---- butterfly reduce the 4 gate sums across the wave ----
        #pragma unroll
        for (int m = 1; m < 64; m <<= 1) {
            s0 += __shfl_xor(s0, m);
            s1 += __shfl_xor(s1, m);
            s2 += __shfl_xor(s2, m);
            s3 += __shfl_xor(s3, m);
        }

        // xg values live on lanes 0..3 (gate 0..3); gather to lane 0
        float xg1 = __shfl(xgv, 1);
        float xg2 = __shfl(xgv, 2);
        float xg3 = __shfl(xgv, 3);

        if (l == 0) {
            float gi = s0 + xgv;
            float gf = s1 + xg1;
            float gg = s2 + xg2;
            float go = s3 + xg3;
            float si = fast_sigmoid(gi);
            float sf = fast_sigmoid(gf);
            float tg = fast_tanh(gg);
            float so = fast_sigmoid(go);
            c_state = sf * c_state + si * tg;
            float hval = so * fast_tanh(c_state);
            u64 pk = ((u64)(unsigned)(t + 1) << 32) | (u64)__float_as_uint(hval);
            __hip_atomic_store(hp + (size_t)(t & 1) * HID + unit, pk,
                               __ATOMIC_RELAXED, __HIP_MEMORY_SCOPE_AGENT);
        }

        // prefetch next xg row (hides under next poll window)
        if (t + 1 < T_SEQ && l < 4) {
            xgv = xgd[(size_t)(t + 1) * 4096 + (size_t)l * HID + unit];
            asm volatile("" : "+v"(xgv));
        }
    }
}

// ---------------- head
__global__ void head_kernel(const float* __restrict__ W_ho,
                            const float* __restrict__ b_ho,
                            const u64* __restrict__ hpack,
                            float* __restrict__ out)
{
    const u64* hf  = hpack + 1 * HID;            // dir0 buf1
    const u64* hbk = hpack + 2 * HID + 1 * HID;  // dir1 buf1
    __shared__ float r0[4], r1[4], r2[4];
    int tid = threadIdx.x;  // 256
    float p0 = 0.f, p1 = 0.f, p2 = 0.f;
    for (int i = tid; i < 2 * HID; i += 256) {
        u64 e = (i < HID) ? hf[i] : hbk[i - HID];
        float hv = __uint_as_float((unsigned)(e & 0xffffffffu));
        p0 += W_ho[0 * 2 * HID + i] * hv;
        p1 += W_ho[1 * 2 * HID + i] * hv;
        p2 += W_ho[2 * 2 * HID + i] * hv;
    }
    #pragma unroll
    for (int m = 1; m < 64; m <<= 1) {
        p0 += __shfl_xor(p0, m);
        p1 += __shfl_xor(p1, m);
        p2 += __shfl_xor(p2, m);
    }
    int w = tid >> 6;
    if ((tid & 63) == 0) { r0[w] = p0; r1[w] = p1; r2[w] = p2; }
    __syncthreads();
    if (tid == 0) {
        out[0] = b_ho[0] + r0[0] + r0[1] + r0[2] + r0[3];
        out[1] = b_ho[1] + r1[0] + r1[1] + r1[2] + r1[3];
        out[2] = b_ho[2] + r2[0] + r2[1] + r2[2] + r2[3];
    }
}

extern "C" void kernel_launch(void* const* d_in, const int* in_sizes, int n_in,
                              void* d_out, int out_size, void* d_ws, size_t ws_size,
                              hipStream_t stream) {
    const float* x     = (const float*)d_in[0];
    const float* Wih_f = (const float*)d_in[1];
    const float* Whh_f = (const float*)d_in[2];
    const float* bih_f = (const float*)d_in[3];
    const float* bhh_f = (const float*)d_in[4];
    const float* Wih_b = (const float*)d_in[5];
    const float* Whh_b = (const float*)d_in[6];
    const float* bih_b = (const float*)d_in[7];
    const float* bhh_b = (const float*)d_in[8];
    const float* W_ho  = (const float*)d_in[9];
    const float* b_ho  = (const float*)d_in[10];

    u64* hpack = (u64*)d_ws;                       // 32 KB packed (tag|h)
    float* xg = (float*)((char*)d_ws + 32768);     // 128 MB xg buffer

    // zero tags every call (ws poisoned once, never re-poisoned between replays)
    hipMemsetAsync(d_ws, 0, 2 * 2 * HID * sizeof(u64), stream);

    dim3 gg(4096 / GN, T_SEQ / GM, 2);
    xproj_gemm<<<gg, 256, 0, stream>>>(x, Wih_f, bih_f, bhh_f,
                                       Wih_b, bih_b, bhh_b, xg);
    bilstm_rec<<<NB_TOT, NTHR, 0, stream>>>(xg, Whh_f, Whh_b, hpack);
    head_kernel<<<1, 256, 0, stream>>>(W_ho, b_ho, hpack, (float*)d_out);
}

// Round 6
// 8998.355 us; speedup vs baseline: 1.5100x; 1.0325x over previous
//
#include <hip/hip_runtime.h>
#include <stdint.h>

// Bidirectional LSTM T=4096, B=1, I=H=1024 -> 3 classes.
// R6: same structure as R5 (named float4 weight regs, wave-per-unit, octet
//     -correct XOR swizzle, packed (epoch|h) u64 dataflow sync), with ONE
//     change: amdgpu_waves_per_eu(2,2) pins the VGPR budget at 256 so the
//     occupancy-greedy allocator (R3: VGPR=52, R5: VGPR=60 -- both <=64,
//     i.e. 8-waves/EU greed) has no incentive to spill the 64 weight regs.

#define T_SEQ 4096
#define ISZ   1024
#define HID   1024
#define NB_TOT 256
#define NTHR  512

typedef unsigned long long u64;

__device__ __forceinline__ float fast_sigmoid(float x) {
    return 1.0f / (1.0f + __expf(-x));
}
__device__ __forceinline__ float fast_tanh(float x) {
    return 1.0f - 2.0f / (__expf(2.0f * x) + 1.0f);
}

#define PIN4(v) asm volatile("" : "+v"(v.x), "+v"(v.y), "+v"(v.z), "+v"(v.w))
#define DOT4(a, b) ((a).x*(b).x + (a).y*(b).y + (a).z*(b).z + (a).w*(b).w)

// ---------------- Phase 1: xg[dir][t][g] = dot(x[row(t)], Wih[g]) + bih[g] + bhh[g]
#define GM 64
#define GN 64
#define GK 32

__global__ __launch_bounds__(256)
void xproj_gemm(const float* __restrict__ x,
                const float* __restrict__ Wih_f, const float* __restrict__ bih_f,
                const float* __restrict__ bhh_f,
                const float* __restrict__ Wih_b, const float* __restrict__ bih_b,
                const float* __restrict__ bhh_b,
                float* __restrict__ xg)
{
    const int dir = blockIdx.z;
    const float* Wih = dir ? Wih_b : Wih_f;
    const float* bih = dir ? bih_b : bih_f;
    const float* bhh = dir ? bhh_b : bhh_f;
    const int m0 = blockIdx.y * GM;
    const int n0 = blockIdx.x * GN;
    const int tid = threadIdx.x;
    const int ms = tid >> 2;
    const int kq = tid & 3;
    const int tm = tid >> 4;
    const int tn = tid & 15;

    __shared__ float As[GK][GM + 4];
    __shared__ float Bs[GK][GN + 4];

    float acc[4][4] = {};

    const int mrow = m0 + ms;
    const int xrow = dir ? (T_SEQ - 1 - mrow) : mrow;
    const float* ap = x + (size_t)xrow * ISZ + kq * 8;
    const float* bp = Wih + (size_t)(n0 + ms) * ISZ + kq * 8;

    for (int k0 = 0; k0 < ISZ; k0 += GK) {
        float4 a0 = *(const float4*)(ap + k0);
        float4 a1 = *(const float4*)(ap + k0 + 4);
        float4 b0 = *(const float4*)(bp + k0);
        float4 b1 = *(const float4*)(bp + k0 + 4);
        __syncthreads();
        const int kb = kq * 8;
        As[kb+0][ms]=a0.x; As[kb+1][ms]=a0.y; As[kb+2][ms]=a0.z; As[kb+3][ms]=a0.w;
        As[kb+4][ms]=a1.x; As[kb+5][ms]=a1.y; As[kb+6][ms]=a1.z; As[kb+7][ms]=a1.w;
        Bs[kb+0][ms]=b0.x; Bs[kb+1][ms]=b0.y; Bs[kb+2][ms]=b0.z; Bs[kb+3][ms]=b0.w;
        Bs[kb+4][ms]=b1.x; Bs[kb+5][ms]=b1.y; Bs[kb+6][ms]=b1.z; Bs[kb+7][ms]=b1.w;
        __syncthreads();
        #pragma unroll
        for (int k = 0; k < GK; ++k) {
            float4 av = *(const float4*)&As[k][tm * 4];
            float4 bv = *(const float4*)&Bs[k][tn * 4];
            acc[0][0] += av.x*bv.x; acc[0][1] += av.x*bv.y; acc[0][2] += av.x*bv.z; acc[0][3] += av.x*bv.w;
            acc[1][0] += av.y*bv.x; acc[1][1] += av.y*bv.y; acc[1][2] += av.y*bv.z; acc[1][3] += av.y*bv.w;
            acc[2][0] += av.z*bv.x; acc[2][1] += av.z*bv.y; acc[2][2] += av.z*bv.z; acc[2][3] += av.z*bv.w;
            acc[3][0] += av.w*bv.x; acc[3][1] += av.w*bv.y; acc[3][2] += av.w*bv.z; acc[3][3] += av.w*bv.w;
        }
    }

    const int gc = n0 + tn * 4;
    float4 bb1 = *(const float4*)(bih + gc);
    float4 bb2 = *(const float4*)(bhh + gc);
    float bx = bb1.x + bb2.x, by = bb1.y + bb2.y, bz = bb1.z + bb2.z, bw = bb1.w + bb2.w;
    float* op = xg + ((size_t)dir << 24) + (size_t)(m0 + tm * 4) * 4096 + gc;
    #pragma unroll
    for (int i = 0; i < 4; ++i) {
        float4 v;
        v.x = acc[i][0] + bx; v.y = acc[i][1] + by;
        v.z = acc[i][2] + bz; v.w = acc[i][3] + bw;
        *(float4*)(op + (size_t)i * 4096) = v;
    }
}

// ---------------- Phase 2: persistent recurrence, register-resident Whh
__global__ __attribute__((amdgpu_flat_work_group_size(NTHR, NTHR)))
           __attribute__((amdgpu_waves_per_eu(2, 2)))
void bilstm_rec(const float* __restrict__ xg,
                const float* __restrict__ Whh_f, const float* __restrict__ Whh_b,
                u64* hpack)
{
    const int tid = threadIdx.x;
    const int blk = blockIdx.x;
    const int dir = blk >> 7;
    const int lb  = blk & 127;
    const int u0  = lb * 8;
    const int w   = tid >> 6;      // wave index -> unit u0+w
    const int l   = tid & 63;      // lane: owns k in [16l, 16l+16) for 4 gates
    const int unit = u0 + w;
    const int xsh = ((l >> 1) & 3) << 2;   // read-side float-offset XOR

    const float* Whh = dir ? Whh_b : Whh_f;
    const float* xgd = xg + ((size_t)dir << 24);
    u64* hp = hpack + (size_t)dir * 2 * HID;

    __shared__ __align__(16) float lds_h[2][HID];

    // ---- one-time: 16 NAMED float4 weight fragments (64 floats) ----
    const float* wp0 = Whh + (size_t)(0 * HID + unit) * HID + l * 16;
    const float* wp1 = Whh + (size_t)(1 * HID + unit) * HID + l * 16;
    const float* wp2 = Whh + (size_t)(2 * HID + unit) * HID + l * 16;
    const float* wp3 = Whh + (size_t)(3 * HID + unit) * HID + l * 16;
    float4 w00 = *(const float4*)(wp0 + 0),  w01 = *(const float4*)(wp0 + 4);
    float4 w02 = *(const float4*)(wp0 + 8),  w03 = *(const float4*)(wp0 + 12);
    float4 w10 = *(const float4*)(wp1 + 0),  w11 = *(const float4*)(wp1 + 4);
    float4 w12 = *(const float4*)(wp1 + 8),  w13 = *(const float4*)(wp1 + 12);
    float4 w20 = *(const float4*)(wp2 + 0),  w21 = *(const float4*)(wp2 + 4);
    float4 w22 = *(const float4*)(wp2 + 8),  w23 = *(const float4*)(wp2 + 12);
    float4 w30 = *(const float4*)(wp3 + 0),  w31 = *(const float4*)(wp3 + 4);
    float4 w32 = *(const float4*)(wp3 + 8),  w33 = *(const float4*)(wp3 + 12);
    PIN4(w00); PIN4(w01); PIN4(w02); PIN4(w03);
    PIN4(w10); PIN4(w11); PIN4(w12); PIN4(w13);
    PIN4(w20); PIN4(w21); PIN4(w22); PIN4(w23);
    PIN4(w30); PIN4(w31); PIN4(w32); PIN4(w33);

    float c_state = 0.0f;          // lane 0 of each wave
    float xgv = 0.0f;              // lanes 0..3 carry gate 0..3 bias+x proj
    if (l < 4) xgv = xgd[(size_t)l * HID + unit];
    asm volatile("" : "+v"(xgv));

    bool dead = false;

    for (int t = 0; t < T_SEQ; ++t) {
        float s0 = 0.f, s1 = 0.f, s2 = 0.f, s3 = 0.f;

        if (t > 0) {
            // ---- stage h(t-1): poll 2 packed words, write swizzled to LDS ----
            const int b = (t - 1) & 1;
            u64* src = hp + (size_t)b * HID;
            const int k0 = tid * 2;
            u64 e0 = 0, e1 = 0;
            if (!dead) {
                int sp = 0;
                while (((e0 = __hip_atomic_load(src + k0, __ATOMIC_RELAXED,
                                                __HIP_MEMORY_SCOPE_AGENT)) >> 32)
                       != (unsigned)t) {
                    if (++sp > (1 << 21)) { dead = true; break; }
                }
                sp = 0;
                if (!dead) {
                    while (((e1 = __hip_atomic_load(src + k0 + 1, __ATOMIC_RELAXED,
                                                    __HIP_MEMORY_SCOPE_AGENT)) >> 32)
                           != (unsigned)t) {
                        if (++sp > (1 << 21)) { dead = true; break; }
                    }
                }
            }
            // store-side swizzle: element k -> (k & ~15) | ((k&15) ^ (((k>>5)&3)<<2))
            const int mi = (k0 & ~15) | ((k0 & 15) ^ (((k0 >> 5) & 3) << 2));
            float2 hv;
            hv.x = __uint_as_float((unsigned)(e0 & 0xffffffffu));
            hv.y = __uint_as_float((unsigned)(e1 & 0xffffffffu));
            *(float2*)&lds_h[b][mi] = hv;
            __syncthreads();

            // ---- 4 conflict-free b128 reads of this lane's 16-float h chunk ----
            const float* lh = &lds_h[b][l * 16];
            float4 h0 = *(const float4*)(lh + (0  ^ xsh));
            float4 h1 = *(const float4*)(lh + (4  ^ xsh));
            float4 h2 = *(const float4*)(lh + (8  ^ xsh));
            float4 h3 = *(const float4*)(lh + (12 ^ xsh));

            s0 = DOT4(w00,h0) + DOT4(w01,h1) + DOT4(w02,h2) + DOT4(w03,h3);
            s1 = DOT4(w10,h0) + DOT4(w11,h1) + DOT4(w12,h2) + DOT4(w13,h3);
            s2 = DOT4(w20,h0) + DOT4(w21,h1) + DOT4(w22,h2) + DOT4(w23,h3);
            s3 = DOT4(w30,h0) + DOT4(w31,h1) + DOT4(w32,h2) + DOT4(w33,h3);
        }

        // ---- butterfly reduce the 4 gate sums across the wave ----
        #pragma unroll
        for (int m = 1; m < 64; m <<= 1) {
            s0 += __shfl_xor(s0, m);
            s1 += __shfl_xor(s1, m);
            s2 += __shfl_xor(s2, m);
            s3 += __shfl_xor(s3, m);
        }

        // xg values live on lanes 0..3 (gate 0..3); gather to lane 0
        float xg1 = __shfl(xgv, 1);
        float xg2 = __shfl(xgv, 2);
        float xg3 = __shfl(xgv, 3);

        if (l == 0) {
            float gi = s0 + xgv;
            float gf = s1 + xg1;
            float gg = s2 + xg2;
            float go = s3 + xg3;
            float si = fast_sigmoid(gi);
            float sf = fast_sigmoid(gf);
            float tg = fast_tanh(gg);
            float so = fast_sigmoid(go);
            c_state = sf * c_state + si * tg;
            float hval = so * fast_tanh(c_state);
            u64 pk = ((u64)(unsigned)(t + 1) << 32) | (u64)__float_as_uint(hval);
            __hip_atomic_store(hp + (size_t)(t & 1) * HID + unit, pk,
                               __ATOMIC_RELAXED, __HIP_MEMORY_SCOPE_AGENT);
        }

        // prefetch next xg row (hides under next poll window)
        if (t + 1 < T_SEQ && l < 4) {
            xgv = xgd[(size_t)(t + 1) * 4096 + (size_t)l * HID + unit];
            asm volatile("" : "+v"(xgv));
        }
    }
}

// ---------------- head
__global__ void head_kernel(const float* __restrict__ W_ho,
                            const float* __restrict__ b_ho,
                            const u64* __restrict__ hpack,
                            float* __restrict__ out)
{
    const u64* hf  = hpack + 1 * HID;            // dir0 buf1
    const u64* hbk = hpack + 2 * HID + 1 * HID;  // dir1 buf1
    __shared__ float r0[4], r1[4], r2[4];
    int tid = threadIdx.x;  // 256
    float p0 = 0.f, p1 = 0.f, p2 = 0.f;
    for (int i = tid; i < 2 * HID; i += 256) {
        u64 e = (i < HID) ? hf[i] : hbk[i - HID];
        float hv = __uint_as_float((unsigned)(e & 0xffffffffu));
        p0 += W_ho[0 * 2 * HID + i] * hv;
        p1 += W_ho[1 * 2 * HID + i] * hv;
        p2 += W_ho[2 * 2 * HID + i] * hv;
    }
    #pragma unroll
    for (int m = 1; m < 64; m <<= 1) {
        p0 += __shfl_xor(p0, m);
        p1 += __shfl_xor(p1, m);
        p2 += __shfl_xor(p2, m);
    }
    int w = tid >> 6;
    if ((tid & 63) == 0) { r0[w] = p0; r1[w] = p1; r2[w] = p2; }
    __syncthreads();
    if (tid == 0) {
        out[0] = b_ho[0] + r0[0] + r0[1] + r0[2] + r0[3];
        out[1] = b_ho[1] + r1[0] + r1[1] + r1[2] + r1[3];
        out[2] = b_ho[2] + r2[0] + r2[1] + r2[2] + r2[3];
    }
}

extern "C" void kernel_launch(void* const* d_in, const int* in_sizes, int n_in,
                              void* d_out, int out_size, void* d_ws, size_t ws_size,
                              hipStream_t stream) {
    const float* x     = (const float*)d_in[0];
    const float* Wih_f = (const float*)d_in[1];
    const float* Whh_f = (const float*)d_in[2];
    const float* bih_f = (const float*)d_in[3];
    const float* bhh_f = (const float*)d_in[4];
    const float* Wih_b = (const float*)d_in[5];
    const float* Whh_b = (const float*)d_in[6];
    const float* bih_b = (const float*)d_in[7];
    const float* bhh_b = (const float*)d_in[8];
    const float* W_ho  = (const float*)d_in[9];
    const float* b_ho  = (const float*)d_in[10];

    u64* hpack = (u64*)d_ws;                       // 32 KB packed (tag|h)
    float* xg = (float*)((char*)d_ws + 32768);     // 128 MB xg buffer

    // zero tags every call (ws poisoned once, never re-poisoned between replays)
    hipMemsetAsync(d_ws, 0, 2 * 2 * HID * sizeof(u64), stream);

    dim3 gg(4096 / GN, T_SEQ / GM, 2);
    xproj_gemm<<<gg, 256, 0, stream>>>(x, Wih_f, bih_f, bhh_f,
                                       Wih_b, bih_b, bhh_b, xg);
    bilstm_rec<<<NB_TOT, NTHR, 0, stream>>>(xg, Whh_f, Whh_b, hpack);
    head_kernel<<<1, 256, 0, stream>>>(W_ho, b_ho, hpack, (float*)d_out);
}

// Round 7
// 8990.351 us; speedup vs baseline: 1.5113x; 1.0009x over previous
//
#include <hip/hip_runtime.h>
#include <stdint.h>

// Bidirectional LSTM T=4096, B=1, I=H=1024 -> 3 classes.
// R7: R6 structure (named float4 weight regs, wave-per-unit, XOR-swizzled
//     h staging, packed (epoch|h) u64 dataflow sync, waves_per_eu(2,2)).
//     ONE change: fused poll -- both packed words polled in a single loop
//     iteration (back-to-back loads -> 1 RTT instead of 2 serial) with
//     s_sleep(1) backoff between failed rounds to cut the L3 poll storm.

#define T_SEQ 4096
#define ISZ   1024
#define HID   1024
#define NB_TOT 256
#define NTHR  512

typedef unsigned long long u64;

__device__ __forceinline__ float fast_sigmoid(float x) {
    return 1.0f / (1.0f + __expf(-x));
}
__device__ __forceinline__ float fast_tanh(float x) {
    return 1.0f - 2.0f / (__expf(2.0f * x) + 1.0f);
}

#define PIN4(v) asm volatile("" : "+v"(v.x), "+v"(v.y), "+v"(v.z), "+v"(v.w))
#define DOT4(a, b) ((a).x*(b).x + (a).y*(b).y + (a).z*(b).z + (a).w*(b).w)

// ---------------- Phase 1: xg[dir][t][g] = dot(x[row(t)], Wih[g]) + bih[g] + bhh[g]
#define GM 64
#define GN 64
#define GK 32

__global__ __launch_bounds__(256)
void xproj_gemm(const float* __restrict__ x,
                const float* __restrict__ Wih_f, const float* __restrict__ bih_f,
                const float* __restrict__ bhh_f,
                const float* __restrict__ Wih_b, const float* __restrict__ bih_b,
                const float* __restrict__ bhh_b,
                float* __restrict__ xg)
{
    const int dir = blockIdx.z;
    const float* Wih = dir ? Wih_b : Wih_f;
    const float* bih = dir ? bih_b : bih_f;
    const float* bhh = dir ? bhh_b : bhh_f;
    const int m0 = blockIdx.y * GM;
    const int n0 = blockIdx.x * GN;
    const int tid = threadIdx.x;
    const int ms = tid >> 2;
    const int kq = tid & 3;
    const int tm = tid >> 4;
    const int tn = tid & 15;

    __shared__ float As[GK][GM + 4];
    __shared__ float Bs[GK][GN + 4];

    float acc[4][4] = {};

    const int mrow = m0 + ms;
    const int xrow = dir ? (T_SEQ - 1 - mrow) : mrow;
    const float* ap = x + (size_t)xrow * ISZ + kq * 8;
    const float* bp = Wih + (size_t)(n0 + ms) * ISZ + kq * 8;

    for (int k0 = 0; k0 < ISZ; k0 += GK) {
        float4 a0 = *(const float4*)(ap + k0);
        float4 a1 = *(const float4*)(ap + k0 + 4);
        float4 b0 = *(const float4*)(bp + k0);
        float4 b1 = *(const float4*)(bp + k0 + 4);
        __syncthreads();
        const int kb = kq * 8;
        As[kb+0][ms]=a0.x; As[kb+1][ms]=a0.y; As[kb+2][ms]=a0.z; As[kb+3][ms]=a0.w;
        As[kb+4][ms]=a1.x; As[kb+5][ms]=a1.y; As[kb+6][ms]=a1.z; As[kb+7][ms]=a1.w;
        Bs[kb+0][ms]=b0.x; Bs[kb+1][ms]=b0.y; Bs[kb+2][ms]=b0.z; Bs[kb+3][ms]=b0.w;
        Bs[kb+4][ms]=b1.x; Bs[kb+5][ms]=b1.y; Bs[kb+6][ms]=b1.z; Bs[kb+7][ms]=b1.w;
        __syncthreads();
        #pragma unroll
        for (int k = 0; k < GK; ++k) {
            float4 av = *(const float4*)&As[k][tm * 4];
            float4 bv = *(const float4*)&Bs[k][tn * 4];
            acc[0][0] += av.x*bv.x; acc[0][1] += av.x*bv.y; acc[0][2] += av.x*bv.z; acc[0][3] += av.x*bv.w;
            acc[1][0] += av.y*bv.x; acc[1][1] += av.y*bv.y; acc[1][2] += av.y*bv.z; acc[1][3] += av.y*bv.w;
            acc[2][0] += av.z*bv.x; acc[2][1] += av.z*bv.y; acc[2][2] += av.z*bv.z; acc[2][3] += av.z*bv.w;
            acc[3][0] += av.w*bv.x; acc[3][1] += av.w*bv.y; acc[3][2] += av.w*bv.z; acc[3][3] += av.w*bv.w;
        }
    }

    const int gc = n0 + tn * 4;
    float4 bb1 = *(const float4*)(bih + gc);
    float4 bb2 = *(const float4*)(bhh + gc);
    float bx = bb1.x + bb2.x, by = bb1.y + bb2.y, bz = bb1.z + bb2.z, bw = bb1.w + bb2.w;
    float* op = xg + ((size_t)dir << 24) + (size_t)(m0 + tm * 4) * 4096 + gc;
    #pragma unroll
    for (int i = 0; i < 4; ++i) {
        float4 v;
        v.x = acc[i][0] + bx; v.y = acc[i][1] + by;
        v.z = acc[i][2] + bz; v.w = acc[i][3] + bw;
        *(float4*)(op + (size_t)i * 4096) = v;
    }
}

// ---------------- Phase 2: persistent recurrence, register-resident Whh
__global__ __attribute__((amdgpu_flat_work_group_size(NTHR, NTHR)))
           __attribute__((amdgpu_waves_per_eu(2, 2)))
void bilstm_rec(const float* __restrict__ xg,
                const float* __restrict__ Whh_f, const float* __restrict__ Whh_b,
                u64* hpack)
{
    const int tid = threadIdx.x;
    const int blk = blockIdx.x;
    const int dir = blk >> 7;
    const int lb  = blk & 127;
    const int u0  = lb * 8;
    const int w   = tid >> 6;      // wave index -> unit u0+w
    const int l   = tid & 63;      // lane: owns k in [16l, 16l+16) for 4 gates
    const int unit = u0 + w;
    const int xsh = ((l >> 1) & 3) << 2;   // read-side float-offset XOR

    const float* Whh = dir ? Whh_b : Whh_f;
    const float* xgd = xg + ((size_t)dir << 24);
    u64* hp = hpack + (size_t)dir * 2 * HID;

    __shared__ __align__(16) float lds_h[2][HID];

    // ---- one-time: 16 NAMED float4 weight fragments (64 floats) ----
    const float* wp0 = Whh + (size_t)(0 * HID + unit) * HID + l * 16;
    const float* wp1 = Whh + (size_t)(1 * HID + unit) * HID + l * 16;
    const float* wp2 = Whh + (size_t)(2 * HID + unit) * HID + l * 16;
    const float* wp3 = Whh + (size_t)(3 * HID + unit) * HID + l * 16;
    float4 w00 = *(const float4*)(wp0 + 0),  w01 = *(const float4*)(wp0 + 4);
    float4 w02 = *(const float4*)(wp0 + 8),  w03 = *(const float4*)(wp0 + 12);
    float4 w10 = *(const float4*)(wp1 + 0),  w11 = *(const float4*)(wp1 + 4);
    float4 w12 = *(const float4*)(wp1 + 8),  w13 = *(const float4*)(wp1 + 12);
    float4 w20 = *(const float4*)(wp2 + 0),  w21 = *(const float4*)(wp2 + 4);
    float4 w22 = *(const float4*)(wp2 + 8),  w23 = *(const float4*)(wp2 + 12);
    float4 w30 = *(const float4*)(wp3 + 0),  w31 = *(const float4*)(wp3 + 4);
    float4 w32 = *(const float4*)(wp3 + 8),  w33 = *(const float4*)(wp3 + 12);
    PIN4(w00); PIN4(w01); PIN4(w02); PIN4(w03);
    PIN4(w10); PIN4(w11); PIN4(w12); PIN4(w13);
    PIN4(w20); PIN4(w21); PIN4(w22); PIN4(w23);
    PIN4(w30); PIN4(w31); PIN4(w32); PIN4(w33);

    float c_state = 0.0f;          // lane 0 of each wave
    float xgv = 0.0f;              // lanes 0..3 carry gate 0..3 bias+x proj
    if (l < 4) xgv = xgd[(size_t)l * HID + unit];
    asm volatile("" : "+v"(xgv));

    bool dead = false;

    for (int t = 0; t < T_SEQ; ++t) {
        float s0 = 0.f, s1 = 0.f, s2 = 0.f, s3 = 0.f;

        if (t > 0) {
            // ---- stage h(t-1): FUSED poll of both packed words (1 RTT),
            //      s_sleep backoff between failed rounds ----
            const int b = (t - 1) & 1;
            u64* src = hp + (size_t)b * HID;
            const int k0 = tid * 2;
            u64 e0 = 0, e1 = 0;
            if (!dead) {
                int sp = 0;
                for (;;) {
                    e0 = __hip_atomic_load(src + k0,     __ATOMIC_RELAXED,
                                           __HIP_MEMORY_SCOPE_AGENT);
                    e1 = __hip_atomic_load(src + k0 + 1, __ATOMIC_RELAXED,
                                           __HIP_MEMORY_SCOPE_AGENT);
                    if (((unsigned)(e0 >> 32) == (unsigned)t) &
                        ((unsigned)(e1 >> 32) == (unsigned)t)) break;
                    if (++sp > (1 << 21)) { dead = true; break; }
                    __builtin_amdgcn_s_sleep(1);
                }
            }
            // store-side swizzle: element k -> (k & ~15) | ((k&15) ^ (((k>>5)&3)<<2))
            const int mi = (k0 & ~15) | ((k0 & 15) ^ (((k0 >> 5) & 3) << 2));
            float2 hv;
            hv.x = __uint_as_float((unsigned)(e0 & 0xffffffffu));
            hv.y = __uint_as_float((unsigned)(e1 & 0xffffffffu));
            *(float2*)&lds_h[b][mi] = hv;
            __syncthreads();

            // ---- 4 conflict-free b128 reads of this lane's 16-float h chunk ----
            const float* lh = &lds_h[b][l * 16];
            float4 h0 = *(const float4*)(lh + (0  ^ xsh));
            float4 h1 = *(const float4*)(lh + (4  ^ xsh));
            float4 h2 = *(const float4*)(lh + (8  ^ xsh));
            float4 h3 = *(const float4*)(lh + (12 ^ xsh));

            s0 = DOT4(w00,h0) + DOT4(w01,h1) + DOT4(w02,h2) + DOT4(w03,h3);
            s1 = DOT4(w10,h0) + DOT4(w11,h1) + DOT4(w12,h2) + DOT4(w13,h3);
            s2 = DOT4(w20,h0) + DOT4(w21,h1) + DOT4(w22,h2) + DOT4(w23,h3);
            s3 = DOT4(w30,h0) + DOT4(w31,h1) + DOT4(w32,h2) + DOT4(w33,h3);
        }

        // ---- butterfly reduce the 4 gate sums across the wave ----
        #pragma unroll
        for (int m = 1; m < 64; m <<= 1) {
            s0 += __shfl_xor(s0, m);
            s1 += __shfl_xor(s1, m);
            s2 += __shfl_xor(s2, m);
            s3 += __shfl_xor(s3, m);
        }

        // xg values live on lanes 0..3 (gate 0..3); gather to lane 0
        float xg1 = __shfl(xgv, 1);
        float xg2 = __shfl(xgv, 2);
        float xg3 = __shfl(xgv, 3);

        if (l == 0) {
            float gi = s0 + xgv;
            float gf = s1 + xg1;
            float gg = s2 + xg2;
            float go = s3 + xg3;
            float si = fast_sigmoid(gi);
            float sf = fast_sigmoid(gf);
            float tg = fast_tanh(gg);
            float so = fast_sigmoid(go);
            c_state = sf * c_state + si * tg;
            float hval = so * fast_tanh(c_state);
            u64 pk = ((u64)(unsigned)(t + 1) << 32) | (u64)__float_as_uint(hval);
            __hip_atomic_store(hp + (size_t)(t & 1) * HID + unit, pk,
                               __ATOMIC_RELAXED, __HIP_MEMORY_SCOPE_AGENT);
        }

        // prefetch next xg row (hides under next poll window)
        if (t + 1 < T_SEQ && l < 4) {
            xgv = xgd[(size_t)(t + 1) * 4096 + (size_t)l * HID + unit];
            asm volatile("" : "+v"(xgv));
        }
    }
}

// ---------------- head
__global__ void head_kernel(const float* __restrict__ W_ho,
                            const float* __restrict__ b_ho,
                            const u64* __restrict__ hpack,
                            float* __restrict__ out)
{
    const u64* hf  = hpack + 1 * HID;            // dir0 buf1
    const u64* hbk = hpack + 2 * HID + 1 * HID;  // dir1 buf1
    __shared__ float r0[4], r1[4], r2[4];
    int tid = threadIdx.x;  // 256
    float p0 = 0.f, p1 = 0.f, p2 = 0.f;
    for (int i = tid; i < 2 * HID; i += 256) {
        u64 e = (i < HID) ? hf[i] : hbk[i - HID];
        float hv = __uint_as_float((unsigned)(e & 0xffffffffu));
        p0 += W_ho[0 * 2 * HID + i] * hv;
        p1 += W_ho[1 * 2 * HID + i] * hv;
        p2 += W_ho[2 * 2 * HID + i] * hv;
    }
    #pragma unroll
    for (int m = 1; m < 64; m <<= 1) {
        p0 += __shfl_xor(p0, m);
        p1 += __shfl_xor(p1, m);
        p2 += __shfl_xor(p2, m);
    }
    int w = tid >> 6;
    if ((tid & 63) == 0) { r0[w] = p0; r1[w] = p1; r2[w] = p2; }
    __syncthreads();
    if (tid == 0) {
        out[0] = b_ho[0] + r0[0] + r0[1] + r0[2] + r0[3];
        out[1] = b_ho[1] + r1[0] + r1[1] + r1[2] + r1[3];
        out[2] = b_ho[2] + r2[0] + r2[1] + r2[2] + r2[3];
    }
}

extern "C" void kernel_launch(void* const* d_in, const int* in_sizes, int n_in,
                              void* d_out, int out_size, void* d_ws, size_t ws_size,
                              hipStream_t stream) {
    const float* x     = (const float*)d_in[0];
    const float* Wih_f = (const float*)d_in[1];
    const float* Whh_f = (const float*)d_in[2];
    const float* bih_f = (const float*)d_in[3];
    const float* bhh_f = (const float*)d_in[4];
    const float* Wih_b = (const float*)d_in[5];
    const float* Whh_b = (const float*)d_in[6];
    const float* bih_b = (const float*)d_in[7];
    const float* bhh_b = (const float*)d_in[8];
    const float* W_ho  = (const float*)d_in[9];
    const float* b_ho  = (const float*)d_in[10];

    u64* hpack = (u64*)d_ws;                       // 32 KB packed (tag|h)
    float* xg = (float*)((char*)d_ws + 32768);     // 128 MB xg buffer

    // zero tags every call (ws poisoned once, never re-poisoned between replays)
    hipMemsetAsync(d_ws, 0, 2 * 2 * HID * sizeof(u64), stream);

    dim3 gg(4096 / GN, T_SEQ / GM, 2);
    xproj_gemm<<<gg, 256, 0, stream>>>(x, Wih_f, bih_f, bhh_f,
                                       Wih_b, bih_b, bhh_b, xg);
    bilstm_rec<<<NB_TOT, NTHR, 0, stream>>>(xg, Whh_f, Whh_b, hpack);
    head_kernel<<<1, 256, 0, stream>>>(W_ho, b_ho, hpack, (float*)d_out);
}

// Round 8
// 7994.026 us; speedup vs baseline: 1.6997x; 1.1246x over previous
//
#include <hip/hip_runtime.h>
#include <stdint.h>

// Bidirectional LSTM T=4096, B=1, I=H=1024 -> 3 classes.
// R8: R3's fast dataflow shape + R6's resident weights.
//     - lane = (gate q, k-chunk kc): reduce = 4 shfl_xor + 3 gather (vs 24+3)
//     - R3's PAD-68 LDS layout (measured 0 bank conflicts in R3)
//     - activations parallelized on 4 lanes via tanh(x)=2*sigmoid(2x)-1
//     - named float4 pinned weights, waves_per_eu(2,2), fused poll+s_sleep

#define T_SEQ 4096
#define ISZ   1024
#define HID   1024
#define NB_TOT 256
#define NTHR  512
#define PAD   68

typedef unsigned long long u64;

__device__ __forceinline__ float fast_sigmoid(float x) {
    return 1.0f / (1.0f + __expf(-x));
}
__device__ __forceinline__ float fast_tanh(float x) {
    return 1.0f - 2.0f / (__expf(2.0f * x) + 1.0f);
}

#define PIN4(v) asm volatile("" : "+v"(v.x), "+v"(v.y), "+v"(v.z), "+v"(v.w))
#define DOT4(a, b) ((a).x*(b).x + (a).y*(b).y + (a).z*(b).z + (a).w*(b).w)

// ---------------- Phase 1: xg[dir][t][g] = dot(x[row(t)], Wih[g]) + bih[g] + bhh[g]
#define GM 64
#define GN 64
#define GK 32

__global__ __launch_bounds__(256)
void xproj_gemm(const float* __restrict__ x,
                const float* __restrict__ Wih_f, const float* __restrict__ bih_f,
                const float* __restrict__ bhh_f,
                const float* __restrict__ Wih_b, const float* __restrict__ bih_b,
                const float* __restrict__ bhh_b,
                float* __restrict__ xg)
{
    const int dir = blockIdx.z;
    const float* Wih = dir ? Wih_b : Wih_f;
    const float* bih = dir ? bih_b : bih_f;
    const float* bhh = dir ? bhh_b : bhh_f;
    const int m0 = blockIdx.y * GM;
    const int n0 = blockIdx.x * GN;
    const int tid = threadIdx.x;
    const int ms = tid >> 2;
    const int kq = tid & 3;
    const int tm = tid >> 4;
    const int tn = tid & 15;

    __shared__ float As[GK][GM + 4];
    __shared__ float Bs[GK][GN + 4];

    float acc[4][4] = {};

    const int mrow = m0 + ms;
    const int xrow = dir ? (T_SEQ - 1 - mrow) : mrow;
    const float* ap = x + (size_t)xrow * ISZ + kq * 8;
    const float* bp = Wih + (size_t)(n0 + ms) * ISZ + kq * 8;

    for (int k0 = 0; k0 < ISZ; k0 += GK) {
        float4 a0 = *(const float4*)(ap + k0);
        float4 a1 = *(const float4*)(ap + k0 + 4);
        float4 b0 = *(const float4*)(bp + k0);
        float4 b1 = *(const float4*)(bp + k0 + 4);
        __syncthreads();
        const int kb = kq * 8;
        As[kb+0][ms]=a0.x; As[kb+1][ms]=a0.y; As[kb+2][ms]=a0.z; As[kb+3][ms]=a0.w;
        As[kb+4][ms]=a1.x; As[kb+5][ms]=a1.y; As[kb+6][ms]=a1.z; As[kb+7][ms]=a1.w;
        Bs[kb+0][ms]=b0.x; Bs[kb+1][ms]=b0.y; Bs[kb+2][ms]=b0.z; Bs[kb+3][ms]=b0.w;
        Bs[kb+4][ms]=b1.x; Bs[kb+5][ms]=b1.y; Bs[kb+6][ms]=b1.z; Bs[kb+7][ms]=b1.w;
        __syncthreads();
        #pragma unroll
        for (int k = 0; k < GK; ++k) {
            float4 av = *(const float4*)&As[k][tm * 4];
            float4 bv = *(const float4*)&Bs[k][tn * 4];
            acc[0][0] += av.x*bv.x; acc[0][1] += av.x*bv.y; acc[0][2] += av.x*bv.z; acc[0][3] += av.x*bv.w;
            acc[1][0] += av.y*bv.x; acc[1][1] += av.y*bv.y; acc[1][2] += av.y*bv.z; acc[1][3] += av.y*bv.w;
            acc[2][0] += av.z*bv.x; acc[2][1] += av.z*bv.y; acc[2][2] += av.z*bv.z; acc[2][3] += av.z*bv.w;
            acc[3][0] += av.w*bv.x; acc[3][1] += av.w*bv.y; acc[3][2] += av.w*bv.z; acc[3][3] += av.w*bv.w;
        }
    }

    const int gc = n0 + tn * 4;
    float4 bb1 = *(const float4*)(bih + gc);
    float4 bb2 = *(const float4*)(bhh + gc);
    float bx = bb1.x + bb2.x, by = bb1.y + bb2.y, bz = bb1.z + bb2.z, bw = bb1.w + bb2.w;
    float* op = xg + ((size_t)dir << 24) + (size_t)(m0 + tm * 4) * 4096 + gc;
    #pragma unroll
    for (int i = 0; i < 4; ++i) {
        float4 v;
        v.x = acc[i][0] + bx; v.y = acc[i][1] + by;
        v.z = acc[i][2] + bz; v.w = acc[i][3] + bw;
        *(float4*)(op + (size_t)i * 4096) = v;
    }
}

// ---------------- Phase 2: persistent recurrence, register-resident Whh
__global__ __attribute__((amdgpu_flat_work_group_size(NTHR, NTHR)))
           __attribute__((amdgpu_waves_per_eu(2, 2)))
void bilstm_rec(const float* __restrict__ xg,
                const float* __restrict__ Whh_f, const float* __restrict__ Whh_b,
                u64* hpack)
{
    const int tid = threadIdx.x;
    const int blk = blockIdx.x;
    const int dir = blk >> 7;
    const int lb  = blk & 127;
    const int u0  = lb * 8;
    const int w   = tid >> 6;      // wave index -> unit u0+w
    const int l   = tid & 63;
    const int q   = l >> 4;        // gate 0..3 (i,f,g,o)
    const int kc  = l & 15;        // k-chunk: owns h[64kc .. 64kc+64) for gate q
    const int unit = u0 + w;
    const int grow = q * HID + unit;

    const float* Whh = dir ? Whh_b : Whh_f;
    const float* xgd = xg + ((size_t)dir << 24);
    u64* hp = hpack + (size_t)dir * 2 * HID;

    __shared__ __align__(16) float lds_h[2][16 * PAD];

    // ---- one-time: 16 NAMED float4 weight fragments (64 floats, one gate row chunk)
    const float* wp = Whh + (size_t)grow * HID + kc * 64;
    float4 w0 = *(const float4*)(wp + 0),  w1 = *(const float4*)(wp + 4);
    float4 w2 = *(const float4*)(wp + 8),  w3 = *(const float4*)(wp + 12);
    float4 w4 = *(const float4*)(wp + 16), w5 = *(const float4*)(wp + 20);
    float4 w6 = *(const float4*)(wp + 24), w7 = *(const float4*)(wp + 28);
    float4 w8 = *(const float4*)(wp + 32), w9 = *(const float4*)(wp + 36);
    float4 wa = *(const float4*)(wp + 40), wb = *(const float4*)(wp + 44);
    float4 wc = *(const float4*)(wp + 48), wd = *(const float4*)(wp + 52);
    float4 we = *(const float4*)(wp + 56), wf = *(const float4*)(wp + 60);
    PIN4(w0); PIN4(w1); PIN4(w2); PIN4(w3);
    PIN4(w4); PIN4(w5); PIN4(w6); PIN4(w7);
    PIN4(w8); PIN4(w9); PIN4(wa); PIN4(wb);
    PIN4(wc); PIN4(wd); PIN4(we); PIN4(wf);

    // activation constants: tanh(x) = 2*sigmoid(2x)-1 -> uniform sigmoid chain
    const float a_scl = (q == 2) ? 2.0f : 1.0f;   // input scale
    const float a_mul = (q == 2) ? 2.0f : 1.0f;   // output scale
    const float a_add = (q == 2) ? -1.0f : 0.0f;  // output offset

    float c_state = 0.0f;          // lane 0 of each wave
    float xgv = 0.0f;              // kc==0 lanes carry gate q's bias+x proj
    if (kc == 0) xgv = xgd[grow];  // t=0 row
    asm volatile("" : "+v"(xgv));

    bool dead = false;

    for (int t = 0; t < T_SEQ; ++t) {
        float s = 0.0f;

        if (t > 0) {
            // ---- stage h(t-1): fused poll of both packed words, s_sleep backoff
            const int b = (t - 1) & 1;
            u64* src = hp + (size_t)b * HID;
            const int k0 = tid * 2;
            u64 e0 = 0, e1 = 0;
            if (!dead) {
                int sp = 0;
                for (;;) {
                    e0 = __hip_atomic_load(src + k0,     __ATOMIC_RELAXED,
                                           __HIP_MEMORY_SCOPE_AGENT);
                    e1 = __hip_atomic_load(src + k0 + 1, __ATOMIC_RELAXED,
                                           __HIP_MEMORY_SCOPE_AGENT);
                    if (((unsigned)(e0 >> 32) == (unsigned)t) &
                        ((unsigned)(e1 >> 32) == (unsigned)t)) break;
                    if (++sp > (1 << 21)) { dead = true; break; }
                    __builtin_amdgcn_s_sleep(1);
                }
            }
            // PAD-68 layout: word k -> lds[(k>>6)*PAD + (k&63)]  (R3: 0 conflicts)
            float2 hv;
            hv.x = __uint_as_float((unsigned)(e0 & 0xffffffffu));
            hv.y = __uint_as_float((unsigned)(e1 & 0xffffffffu));
            *(float2*)&lds_h[b][(k0 >> 6) * PAD + (k0 & 63)] = hv;
            __syncthreads();

            // ---- 16 b128 reads of this lane's 64-float h chunk ----
            const float* lh = &lds_h[b][kc * PAD];
            float4 h0 = *(const float4*)(lh + 0),  h1 = *(const float4*)(lh + 4);
            float4 h2 = *(const float4*)(lh + 8),  h3 = *(const float4*)(lh + 12);
            float4 h4 = *(const float4*)(lh + 16), h5 = *(const float4*)(lh + 20);
            float4 h6 = *(const float4*)(lh + 24), h7 = *(const float4*)(lh + 28);
            s  = DOT4(w0,h0) + DOT4(w1,h1) + DOT4(w2,h2) + DOT4(w3,h3);
            s += DOT4(w4,h4) + DOT4(w5,h5) + DOT4(w6,h6) + DOT4(w7,h7);
            float4 h8 = *(const float4*)(lh + 32), h9 = *(const float4*)(lh + 36);
            float4 ha = *(const float4*)(lh + 40), hb = *(const float4*)(lh + 44);
            float4 hc = *(const float4*)(lh + 48), hd = *(const float4*)(lh + 52);
            float4 he = *(const float4*)(lh + 56), hf = *(const float4*)(lh + 60);
            s += DOT4(w8,h8) + DOT4(w9,h9) + DOT4(wa,ha) + DOT4(wb,hb);
            s += DOT4(wc,hc) + DOT4(wd,hd) + DOT4(we,he) + DOT4(wf,hf);
        }

        // ---- reduce over the 16 kc lanes (4-stage chain) ----
        s += __shfl_xor(s, 1);
        s += __shfl_xor(s, 2);
        s += __shfl_xor(s, 4);
        s += __shfl_xor(s, 8);

        // kc==0 lanes (l = 0,16,32,48) hold gate preacts; activate in parallel
        float pg = s + xgv;
        float act = a_mul * fast_sigmoid(a_scl * pg) + a_add;

        // gather activated gates to lane 0
        float sf = __shfl(act, 16);
        float tg = __shfl(act, 32);
        float so = __shfl(act, 48);

        if (l == 0) {
            float si = act;
            c_state = sf * c_state + si * tg;
            float hval = so * fast_tanh(c_state);
            u64 pk = ((u64)(unsigned)(t + 1) << 32) | (u64)__float_as_uint(hval);
            __hip_atomic_store(hp + (size_t)(t & 1) * HID + unit, pk,
                               __ATOMIC_RELAXED, __HIP_MEMORY_SCOPE_AGENT);
        }

        // prefetch next xg row (hides under next poll window)
        if (t + 1 < T_SEQ && kc == 0) {
            xgv = xgd[(size_t)(t + 1) * 4096 + grow];
            asm volatile("" : "+v"(xgv));
        }
    }
}

// ---------------- head
__global__ void head_kernel(const float* __restrict__ W_ho,
                            const float* __restrict__ b_ho,
                            const u64* __restrict__ hpack,
                            float* __restrict__ out)
{
    const u64* hf  = hpack + 1 * HID;            // dir0 buf1
    const u64* hbk = hpack + 2 * HID + 1 * HID;  // dir1 buf1
    __shared__ float r0[4], r1[4], r2[4];
    int tid = threadIdx.x;  // 256
    float p0 = 0.f, p1 = 0.f, p2 = 0.f;
    for (int i = tid; i < 2 * HID; i += 256) {
        u64 e = (i < HID) ? hf[i] : hbk[i - HID];
        float hv = __uint_as_float((unsigned)(e & 0xffffffffu));
        p0 += W_ho[0 * 2 * HID + i] * hv;
        p1 += W_ho[1 * 2 * HID + i] * hv;
        p2 += W_ho[2 * 2 * HID + i] * hv;
    }
    #pragma unroll
    for (int m = 1; m < 64; m <<= 1) {
        p0 += __shfl_xor(p0, m);
        p1 += __shfl_xor(p1, m);
        p2 += __shfl_xor(p2, m);
    }
    int w = tid >> 6;
    if ((tid & 63) == 0) { r0[w] = p0; r1[w] = p1; r2[w] = p2; }
    __syncthreads();
    if (tid == 0) {
        out[0] = b_ho[0] + r0[0] + r0[1] + r0[2] + r0[3];
        out[1] = b_ho[1] + r1[0] + r1[1] + r1[2] + r1[3];
        out[2] = b_ho[2] + r2[0] + r2[1] + r2[2] + r2[3];
    }
}

extern "C" void kernel_launch(void* const* d_in, const int* in_sizes, int n_in,
                              void* d_out, int out_size, void* d_ws, size_t ws_size,
                              hipStream_t stream) {
    const float* x     = (const float*)d_in[0];
    const float* Wih_f = (const float*)d_in[1];
    const float* Whh_f = (const float*)d_in[2];
    const float* bih_f = (const float*)d_in[3];
    const float* bhh_f = (const float*)d_in[4];
    const float* Wih_b = (const float*)d_in[5];
    const float* Whh_b = (const float*)d_in[6];
    const float* bih_b = (const float*)d_in[7];
    const float* bhh_b = (const float*)d_in[8];
    const float* W_ho  = (const float*)d_in[9];
    const float* b_ho  = (const float*)d_in[10];

    u64* hpack = (u64*)d_ws;                       // 32 KB packed (tag|h)
    float* xg = (float*)((char*)d_ws + 32768);     // 128 MB xg buffer

    // zero tags every call (ws poisoned once, never re-poisoned between replays)
    hipMemsetAsync(d_ws, 0, 2 * 2 * HID * sizeof(u64), stream);

    dim3 gg(4096 / GN, T_SEQ / GM, 2);
    xproj_gemm<<<gg, 256, 0, stream>>>(x, Wih_f, bih_f, bhh_f,
                                       Wih_b, bih_b, bhh_b, xg);
    bilstm_rec<<<NB_TOT, NTHR, 0, stream>>>(xg, Whh_f, Whh_b, hpack);
    head_kernel<<<1, 256, 0, stream>>>(W_ho, b_ho, hpack, (float*)d_out);
}